// Round 1
// baseline (69.222 us; speedup 1.0000x reference)
//
#include <hip/hip_runtime.h>
#include <hip/hip_bf16.h>

// SurfaceLoss: B=4, P=100000, K=32
//   n_unit  = n / max(||n||, 1e-17)
//   w_k     = exp(-||kn_unit_k - n_unit||^2 / 0.5625)
//   out     = sum(kn_k * w_k) / max(sum(w_k), 1e-17)

#define SL_B 4
#define SL_P 100000
#define SL_K 32
#define SL_INV_SIG2 1.77777779f   // 1/(0.75*0.75)
#define SL_EPS 1e-17f

__global__ __launch_bounds__(256) void SurfaceLoss_kernel(
    const float* __restrict__ normals,   // [B,P,3]
    const int*   __restrict__ knn,       // [B,P,K] (int32)
    float*       __restrict__ out)       // [B,P,3]
{
    int gid = blockIdx.x * blockDim.x + threadIdx.x;
    if (gid >= SL_B * SL_P) return;
    int b = gid / SL_P;

    const float* nb = normals + (size_t)b * SL_P * 3;

    // center normal, unit
    float nx = normals[3 * (size_t)gid + 0];
    float ny = normals[3 * (size_t)gid + 1];
    float nz = normals[3 * (size_t)gid + 2];
    float nlen = sqrtf(nx * nx + ny * ny + nz * nz);
    float ninv = 1.0f / fmaxf(nlen, SL_EPS);
    float ux = nx * ninv, uy = ny * ninv, uz = nz * ninv;

    const int* kptr = knn + (size_t)gid * SL_K;

    float numx = 0.f, numy = 0.f, numz = 0.f, den = 0.f;

#pragma unroll
    for (int k0 = 0; k0 < SL_K; k0 += 4) {
        int4 i4 = *reinterpret_cast<const int4*>(kptr + k0);
        int idxs[4] = {i4.x, i4.y, i4.z, i4.w};
#pragma unroll
        for (int j = 0; j < 4; ++j) {
            int idx = idxs[j];
            float kx = nb[3 * (size_t)idx + 0];
            float ky = nb[3 * (size_t)idx + 1];
            float kz = nb[3 * (size_t)idx + 2];
            float klen = sqrtf(kx * kx + ky * ky + kz * kz);
            float kinv = 1.0f / fmaxf(klen, SL_EPS);
            float dx = kx * kinv - ux;
            float dy = ky * kinv - uy;
            float dz = kz * kinv - uz;
            float d2 = dx * dx + dy * dy + dz * dz;
            float w = __expf(-d2 * SL_INV_SIG2);
            numx = fmaf(kx, w, numx);
            numy = fmaf(ky, w, numy);
            numz = fmaf(kz, w, numz);
            den += w;
        }
    }

    float dinv = 1.0f / fmaxf(den, SL_EPS);  // den > 0 always; guard matches eps_denom
    out[3 * (size_t)gid + 0] = numx * dinv;
    out[3 * (size_t)gid + 1] = numy * dinv;
    out[3 * (size_t)gid + 2] = numz * dinv;
}

extern "C" void kernel_launch(void* const* d_in, const int* in_sizes, int n_in,
                              void* d_out, int out_size, void* d_ws, size_t ws_size,
                              hipStream_t stream) {
    const float* normals = (const float*)d_in[0];
    const int*   knn     = (const int*)d_in[1];
    float*       out     = (float*)d_out;

    int total = SL_B * SL_P;                 // 400000 points
    int block = 256;
    int grid = (total + block - 1) / block;  // 1563 blocks
    SurfaceLoss_kernel<<<grid, block, 0, stream>>>(normals, knn, out);
}